// Round 4
// baseline (307.414 us; speedup 1.0000x reference)
//
#include <hip/hip_runtime.h>
#include <hip/hip_bf16.h>

// GCNConv + ReLU: out = relu( (A_norm @ (x W)) + b ), A_norm = D^-1/2 (A + I) D^-1/2
// Round 10: RESUBMIT of round-9 (container died twice -- infra-distress signals
// in prior timing blocks; source audit found no OOB/hang path). Change under
// test: aggregate = temporally-phased column slicing. xwp stored SLICE-MAJOR
// (8 slices x [npad][32] bf16, 3.2 MB/slice < 4 MB L2/XCD). Blocks ordered
// slice-major => during a slice pass every XCD has the whole slice L2-resident
// => gathers become L2 hits; FETCH 352 MB -> ~205 MB compulsory floor.
// Wave = 8 edge-groups x 8 col-lanes, 32 edges/round (4 independent uint2
// gathers/lane in flight), shfl_xor butterfly folds partials, sentinel zero-row
// (index n) kills tail masking. GEMM (round-8 structure) writes slice-major.

#define FEATS 256
#define MAXBUCK 200   // >= (50000+255)>>8 = 196
#define P1_CAP 64     // LDS slots per bucket per 4096-edge chunk (mean ~21)
#define BCAP 10240    // temp capacity per bucket (mean 8192, ~22 sigma)

typedef __bf16 bf16x8 __attribute__((ext_vector_type(8)));
typedef float f32x4 __attribute__((ext_vector_type(4)));

__device__ __forceinline__ unsigned short f2bf(float f) {  // RNE
  unsigned u = __float_as_uint(f);
  u += 0x7fffu + ((u >> 16) & 1u);
  return (unsigned short)(u >> 16);
}
__device__ __forceinline__ float bflo(unsigned u) { return __uint_as_float(u << 16); }
__device__ __forceinline__ float bfhi(unsigned u) { return __uint_as_float(u & 0xFFFF0000u); }

// ---------------- init: zero bucket cursors + zero sentinel rows of xwp ----------------

__global__ __launch_bounds__(512) void init_misc(int* __restrict__ gcursor, int nbuck,
                                                 int* __restrict__ xwp_i, int npad, int n) {
  const int t = threadIdx.x;
  if (t < nbuck) gcursor[t] = 0;
  const int j = t - 256;           // 128 ints = 8 slices x 64 B sentinel rows
  if (j >= 0 && j < 128) {
    const int s = j >> 4, w = j & 15;
    xwp_i[((size_t)s * npad + n) * 16 + w] = 0;
  }
}

// ---------------- CSR build ----------------

// pass1: bin packed edges (dst<<16|src) by dst>>8. 1024 threads, 4096 edges/block.
__global__ __launch_bounds__(1024) void pass1_bin(const int* __restrict__ src,
                                                  const int* __restrict__ dst,
                                                  int E, int nbuck,
                                                  int* __restrict__ gcursor,
                                                  unsigned* __restrict__ temp) {
  __shared__ unsigned lbuf[MAXBUCK * P1_CAP];  // 51.2 KB
  __shared__ int lcnt[MAXBUCK];
  __shared__ int lbase[MAXBUCK];
  const int tid = threadIdx.x;
  for (int i = tid; i < nbuck; i += 1024) lcnt[i] = 0;
  __syncthreads();

  const int e0 = blockIdx.x * 4096;
  #pragma unroll
  for (int i = 0; i < 4; ++i) {
    int e = e0 + i * 1024 + tid;
    if (e < E) {
      unsigned d = (unsigned)dst[e];
      unsigned p = (d << 16) | (unsigned)src[e];
      int b = (int)(d >> 8);
      int pos = atomicAdd(&lcnt[b], 1);
      if (pos < P1_CAP) {
        lbuf[b * P1_CAP + pos] = p;
      } else {  // rare spill: direct global scatter
        int gp = atomicAdd(&gcursor[b], 1);
        temp[(size_t)b * BCAP + gp] = p;
      }
    }
  }
  __syncthreads();
  if (tid < nbuck) {
    int c = lcnt[tid]; if (c > P1_CAP) c = P1_CAP;
    lcnt[tid] = c;
    lbase[tid] = atomicAdd(&gcursor[tid], c);
  }
  __syncthreads();
  for (int i = tid; i < nbuck * P1_CAP; i += 1024) {
    int b = i >> 6, j = i & (P1_CAP - 1);
    if (j < lcnt[b]) temp[(size_t)b * BCAP + lbase[b] + j] = lbuf[i];
  }
}

// exclusive scan over bucket counts (nbuck <= 256), one block
__global__ __launch_bounds__(256) void scan_buckets(const int* __restrict__ gcursor,
                                                    int* __restrict__ bbase,
                                                    int* __restrict__ row_ptr,
                                                    int nbuck, int n) {
  __shared__ int tmp[256];
  int t = threadIdx.x;
  int v = (t < nbuck) ? min(gcursor[t], BCAP) : 0;
  tmp[t] = v;
  __syncthreads();
  #pragma unroll
  for (int off = 1; off < 256; off <<= 1) {
    int x = (t >= off) ? tmp[t - off] : 0;
    __syncthreads();
    tmp[t] += x;
    __syncthreads();
  }
  if (t < nbuck) bbase[t] = tmp[t] - v;
  if (t == 0) row_ptr[n] = tmp[255];
}

// pass2: per-bucket local CSR. 1024 threads.
__global__ __launch_bounds__(1024) void pass2_csr(const unsigned* __restrict__ temp,
                                                  const int* __restrict__ gcursor,
                                                  const int* __restrict__ bbase,
                                                  unsigned short* __restrict__ csr16,
                                                  int* __restrict__ row_ptr,
                                                  float* __restrict__ dinv, int n) {
  __shared__ unsigned ebuf[BCAP];          // 40 KB
  __shared__ unsigned short sorted[BCAP];  // 20 KB
  __shared__ int hist[256], scn[256], sexcl[256], ofs[256];
  const int b = blockIdx.x;
  const int tid = threadIdx.x;
  int cnt = gcursor[b]; if (cnt > BCAP) cnt = BCAP;
  const int base = bbase[b];
  const unsigned* tp = temp + (size_t)b * BCAP;

  if (tid < 256) { hist[tid] = 0; ofs[tid] = 0; }
  for (int i = tid; i < cnt; i += 1024) ebuf[i] = tp[i];
  __syncthreads();
  for (int i = tid; i < cnt; i += 1024) atomicAdd(&hist[(ebuf[i] >> 16) & 255], 1);
  __syncthreads();

  if (tid < 256) scn[tid] = hist[tid];
  __syncthreads();
  #pragma unroll
  for (int off = 1; off < 256; off <<= 1) {
    int x = 0;
    if (tid < 256 && tid >= off) x = scn[tid - off];
    __syncthreads();
    if (tid < 256) scn[tid] += x;
    __syncthreads();
  }
  if (tid < 256) {
    int v = hist[tid];
    int excl = scn[tid] - v;
    sexcl[tid] = excl;
    int node = (b << 8) + tid;
    if (node < n) {
      row_ptr[node] = base + excl;
      dinv[node] = rsqrtf((float)(v + 1));  // +1 self loop
    }
  }
  __syncthreads();

  for (int i = tid; i < cnt; i += 1024) {
    unsigned e = ebuf[i];
    int dl = (int)((e >> 16) & 255);
    int pos = sexcl[dl] + atomicAdd(&ofs[dl], 1);
    sorted[pos] = (unsigned short)(e & 0xFFFFu);
  }
  __syncthreads();
  for (int i = tid; i < cnt; i += 1024) csr16[base + i] = sorted[i];
}

// ---------------- W transpose + bf16 convert: Wt[n][k] = bf16(W[k][n]) ----------------

__global__ __launch_bounds__(256) void wt_build(const float* __restrict__ W,
                                                unsigned short* __restrict__ Wt) {
  int k = blockIdx.x;
  int nn = threadIdx.x;
  Wt[nn * FEATS + k] = f2bf(W[k * FEATS + nn]);
}

// ---------------- MFMA GEMM (round-8 structure), slice-major epilogue ----------------

__global__ __launch_bounds__(256, 2) void gemm_mfma(const float* __restrict__ x,
                                                    const unsigned short* __restrict__ Wt,
                                                    const float* __restrict__ dinv,
                                                    unsigned short* __restrict__ xwp,
                                                    int M, int npad) {
  __shared__ bf16x8 A_lds[32 * 64];  // [sub*8+kc][lane], 32 KB
  const int wv   = (int)(threadIdx.x >> 6);  // wave id = col-group = conversion sub
  const int lane = (int)(threadIdx.x & 63);
  const int lm   = lane & 15;
  const int quad = lane >> 4;
  const int m0   = (int)blockIdx.x * 64;

  // B panel: loaded once, lives in registers for the whole block
  bf16x8 Bfrag[4][8];
  #pragma unroll
  for (int ct = 0; ct < 4; ++ct) {
    const unsigned short* wrow = Wt + (size_t)(wv * 64 + ct * 16 + lm) * FEATS + quad * 8;
    #pragma unroll
    for (int kc = 0; kc < 8; ++kc)
      Bfrag[ct][kc] = *(const bf16x8*)(wrow + kc * 32);
  }

  // stage A sub = wv
  {
    int arow = m0 + wv * 16 + lm; if (arow >= M) arow = M - 1;
    const float* xrow = x + (size_t)arow * FEATS + quad * 8;
    #pragma unroll
    for (int kc = 0; kc < 8; ++kc) {
      const float4 f0 = *(const float4*)(xrow + kc * 32);
      const float4 f1 = *(const float4*)(xrow + kc * 32 + 4);
      union { bf16x8 v; unsigned short u[8]; } a;
      a.u[0] = f2bf(f0.x); a.u[1] = f2bf(f0.y); a.u[2] = f2bf(f0.z); a.u[3] = f2bf(f0.w);
      a.u[4] = f2bf(f1.x); a.u[5] = f2bf(f1.y); a.u[6] = f2bf(f1.z); a.u[7] = f2bf(f1.w);
      A_lds[(wv * 8 + kc) * 64 + lane] = a.v;
    }
  }
  __syncthreads();

  // compute: 4 row-subs x (8 kc x 4 ct) MFMAs, A from LDS, B from registers
  #pragma unroll
  for (int sub = 0; sub < 4; ++sub) {
    bf16x8 Af[8];
    #pragma unroll
    for (int kc = 0; kc < 8; ++kc) Af[kc] = A_lds[(sub * 8 + kc) * 64 + lane];

    f32x4 acc[4];
    #pragma unroll
    for (int ct = 0; ct < 4; ++ct) acc[ct] = (f32x4){0.f, 0.f, 0.f, 0.f};

    #pragma unroll
    for (int kc = 0; kc < 8; ++kc) {
      #pragma unroll
      for (int ct = 0; ct < 4; ++ct)
        acc[ct] = __builtin_amdgcn_mfma_f32_16x16x32_bf16(Af[kc], Bfrag[ct][kc], acc[ct], 0, 0, 0);
    }

    #pragma unroll
    for (int r = 0; r < 4; ++r) {
      const int row = m0 + sub * 16 + quad * 4 + r;
      if (row < M) {
        const float dd = dinv[row];
        #pragma unroll
        for (int ct = 0; ct < 4; ++ct) {
          const int c = wv * 64 + ct * 16 + lm;
          const int sl = c >> 5, off = c & 31;  // slice-major write
          xwp[((size_t)sl * npad + row) * 32 + off] = f2bf(acc[ct][r] * dd);
        }
      }
    }
  }
}

// ---------------- aggregation: slice-phased gather ----------------
// Wave = 8 edge-groups (eg) x 8 col-lanes (cl). Per round: 32 edges, each lane
// issues 4 independent uint2 gathers (64 B/edge-row within the slice).
// Sentinel row n (zeroed) absorbs all tails -- no masking anywhere.

__global__ __launch_bounds__(256) void aggregate(const unsigned short* __restrict__ xwp,
                                                 const float* __restrict__ dinv,
                                                 const int* __restrict__ row_ptr,
                                                 const unsigned short* __restrict__ csr16,
                                                 const float* __restrict__ bias,
                                                 float* __restrict__ out,
                                                 int n, int npad, int nbps, int sl0) {
  const int sl   = sl0 + (int)(blockIdx.x / nbps);
  const int node = ((int)(blockIdx.x % nbps)) * 4 + (int)(threadIdx.x >> 6);
  const int lane = (int)(threadIdx.x & 63);
  if (node >= n) return;
  const int eg = lane >> 3;
  const int cl = lane & 7;
  // slice base + per-lane column offset; row offset added as sj*32 elems
  const unsigned short* xs = xwp + (size_t)sl * npad * 32 + cl * 4;

  float4 acc = {0.f, 0.f, 0.f, 0.f};
  if (eg == 0) {  // self-loop row, counted once after the butterfly
    uint2 v = *(const uint2*)(xs + (size_t)node * 32);
    acc.x = bflo(v.x); acc.y = bfhi(v.x); acc.z = bflo(v.y); acc.w = bfhi(v.y);
  }

  const int beg = row_ptr[node];
  const int end = row_ptr[node + 1];
  for (int base = beg; base < end; base += 64) {
    int idx = base + lane;
    int sb = (idx < end) ? (int)csr16[idx] : n;  // sentinel -> zero row
    int m = end - base; if (m > 64) m = 64;
    for (int i = 0; i < m; i += 32) {  // 32 edges per round, 4 gathers in flight
      int s0 = __shfl(sb, i + eg);
      int s1 = __shfl(sb, i + 8 + eg);
      int s2 = __shfl(sb, i + 16 + eg);
      int s3 = __shfl(sb, i + 24 + eg);
      uint2 v0 = *(const uint2*)(xs + (size_t)s0 * 32);
      uint2 v1 = *(const uint2*)(xs + (size_t)s1 * 32);
      uint2 v2 = *(const uint2*)(xs + (size_t)s2 * 32);
      uint2 v3 = *(const uint2*)(xs + (size_t)s3 * 32);
      acc.x += bflo(v0.x); acc.y += bfhi(v0.x); acc.z += bflo(v0.y); acc.w += bfhi(v0.y);
      acc.x += bflo(v1.x); acc.y += bfhi(v1.x); acc.z += bflo(v1.y); acc.w += bfhi(v1.y);
      acc.x += bflo(v2.x); acc.y += bfhi(v2.x); acc.z += bflo(v2.y); acc.w += bfhi(v2.y);
      acc.x += bflo(v3.x); acc.y += bfhi(v3.x); acc.z += bflo(v3.y); acc.w += bfhi(v3.y);
    }
  }

  // fold the 8 edge-group partials (strides 8,16,32)
  #pragma unroll
  for (int st = 8; st < 64; st <<= 1) {
    acc.x += __shfl_xor(acc.x, st);
    acc.y += __shfl_xor(acc.y, st);
    acc.z += __shfl_xor(acc.z, st);
    acc.w += __shfl_xor(acc.w, st);
  }

  const float dd = dinv[node];
  const float4 bb = *(const float4*)(bias + sl * 32 + cl * 4);
  f32x4 o;
  o.x = fmaxf(fmaf(acc.x, dd, bb.x), 0.f);
  o.y = fmaxf(fmaf(acc.y, dd, bb.y), 0.f);
  o.z = fmaxf(fmaf(acc.z, dd, bb.z), 0.f);
  o.w = fmaxf(fmaf(acc.w, dd, bb.w), 0.f);
  if (eg == 0)  // NT store: 51 MB output written once; keep xwp in L2
    __builtin_nontemporal_store(o, (f32x4*)(out + (size_t)node * 256 + sl * 32 + cl * 4));
}

// ---------------- launch ----------------

extern "C" void kernel_launch(void* const* d_in, const int* in_sizes, int n_in,
                              void* d_out, int out_size, void* d_ws, size_t ws_size,
                              hipStream_t stream) {
  const float* x  = (const float*)d_in[0];   // [n, 256]
  const int*   ei = (const int*)d_in[1];     // [2, E]
  const float* W  = (const float*)d_in[2];   // [256, 256]
  const float* b  = (const float*)d_in[3];   // [256]

  const int n = in_sizes[0] / FEATS;         // 50000
  const int E = in_sizes[1] / 2;             // 1,600,000
  const int* src = ei;
  const int* dst = ei + E;
  const int nbuck = (n + 255) >> 8;          // 196
  const int npad = n + 1;                    // +1 sentinel zero row per slice

  // workspace layout (bytes); real footprint ~37.4 MB (same as round-2 layout)
  char* ws = (char*)d_ws;
  size_t o0 = 0;
  unsigned short* xwp   = (unsigned short*)(ws + o0); o0 += (size_t)npad * 512;  // 8 slices x npad x 64 B
  unsigned short* Wt    = (unsigned short*)(ws + o0); o0 += 131072;
  float*          dinv  = (float*)(ws + o0);          o0 += 200064;
  int*            row_ptr = (int*)(ws + o0);          o0 += 200064;
  unsigned short* csr16 = (unsigned short*)(ws + o0); o0 += 3200000;
  int*            gcursor = (int*)(ws + o0);          o0 += 1024;
  int*            bbase   = (int*)(ws + o0);          o0 += 1024;
  unsigned*       temp    = (unsigned*)(ws + o0);     o0 += (size_t)nbuck * BCAP * 4;

  hipLaunchKernelGGL(init_misc, dim3(1), dim3(512), 0, stream, gcursor, nbuck, (int*)xwp, npad, n);
  hipLaunchKernelGGL(wt_build, dim3(256), dim3(256), 0, stream, W, Wt);

  const int g_p1 = (E + 4095) / 4096;  // 391
  hipLaunchKernelGGL(pass1_bin, dim3(g_p1), dim3(1024), 0, stream, src, dst, E, nbuck, gcursor, temp);
  hipLaunchKernelGGL(scan_buckets, dim3(1), dim3(256), 0, stream, gcursor, bbase, row_ptr, nbuck, n);
  hipLaunchKernelGGL(pass2_csr, dim3(nbuck), dim3(1024), 0, stream, temp, gcursor, bbase,
                     csr16, row_ptr, dinv, n);

  hipLaunchKernelGGL(gemm_mfma, dim3((n + 63) / 64), dim3(256), 0, stream, x, Wt, dinv, xwp, n, npad);

  // slice-phased aggregate; two launches (slices 0-3, 4-7) for rocprof visibility
  const int nbps = (n + 3) / 4;  // node-blocks per slice
  hipLaunchKernelGGL(aggregate, dim3(nbps * 4), dim3(256), 0, stream,
                     xwp, dinv, row_ptr, csr16, b, (float*)d_out, n, npad, nbps, 0);
  hipLaunchKernelGGL(aggregate, dim3(nbps * 4), dim3(256), 0, stream,
                     xwp, dinv, row_ptr, csr16, b, (float*)d_out, n, npad, nbps, 4);
}

// Round 5
// 260.948 us; speedup vs baseline: 1.1781x; 1.1781x over previous
//
#include <hip/hip_runtime.h>
#include <hip/hip_bf16.h>

// GCNConv + ReLU: out = relu( (A_norm @ (x W)) + b ), A_norm = D^-1/2 (A + I) D^-1/2
// Round 11: hybrid sliced aggregate. Round-10 confirmed slice-phasing cuts FETCH
// 352->132 MB (L2-capacity theory right) but 8x'd per-wave overhead (400K waves,
// butterfly, per-slice prologue) -> VALU-time 35->91 us, net LOSS (165 vs 107).
// New shape: wave = 8 nodes (eg) x 8 col-lanes (cl), slice-phased as before.
// Per iteration: 1 idx load (8x2B bcast) + 1 gather (8 random 64B rows = 512 B
// payload, same economics as the original row-major kernel) + 8 VALU. No
// butterfly, 50K waves/slice-set, 8-deep unroll = 4 KB in flight. Loop runs to
// max-degree of the 8 nodes (~25% sentinel iters, broadcast-cheap).
// Expect: FETCH ~132 MB kept, agg 165 -> 60-85 us, total ~200-230 us.

#define FEATS 256
#define MAXBUCK 200   // >= (50000+255)>>8 = 196
#define P1_CAP 64     // LDS slots per bucket per 4096-edge chunk (mean ~21)
#define BCAP 10240    // temp capacity per bucket (mean 8192, ~22 sigma)

typedef __bf16 bf16x8 __attribute__((ext_vector_type(8)));
typedef float f32x4 __attribute__((ext_vector_type(4)));

__device__ __forceinline__ unsigned short f2bf(float f) {  // RNE
  unsigned u = __float_as_uint(f);
  u += 0x7fffu + ((u >> 16) & 1u);
  return (unsigned short)(u >> 16);
}
__device__ __forceinline__ float bflo(unsigned u) { return __uint_as_float(u << 16); }
__device__ __forceinline__ float bfhi(unsigned u) { return __uint_as_float(u & 0xFFFF0000u); }

// ---------------- init: zero bucket cursors + zero sentinel rows of xwp ----------------

__global__ __launch_bounds__(512) void init_misc(int* __restrict__ gcursor, int nbuck,
                                                 int* __restrict__ xwp_i, int npad, int n) {
  const int t = threadIdx.x;
  if (t < nbuck) gcursor[t] = 0;
  const int j = t - 256;           // 128 ints = 8 slices x 64 B sentinel rows
  if (j >= 0 && j < 128) {
    const int s = j >> 4, w = j & 15;
    xwp_i[((size_t)s * npad + n) * 16 + w] = 0;
  }
}

// ---------------- CSR build ----------------

// pass1: bin packed edges (dst<<16|src) by dst>>8. 1024 threads, 4096 edges/block.
__global__ __launch_bounds__(1024) void pass1_bin(const int* __restrict__ src,
                                                  const int* __restrict__ dst,
                                                  int E, int nbuck,
                                                  int* __restrict__ gcursor,
                                                  unsigned* __restrict__ temp) {
  __shared__ unsigned lbuf[MAXBUCK * P1_CAP];  // 51.2 KB
  __shared__ int lcnt[MAXBUCK];
  __shared__ int lbase[MAXBUCK];
  const int tid = threadIdx.x;
  for (int i = tid; i < nbuck; i += 1024) lcnt[i] = 0;
  __syncthreads();

  const int e0 = blockIdx.x * 4096;
  #pragma unroll
  for (int i = 0; i < 4; ++i) {
    int e = e0 + i * 1024 + tid;
    if (e < E) {
      unsigned d = (unsigned)dst[e];
      unsigned p = (d << 16) | (unsigned)src[e];
      int b = (int)(d >> 8);
      int pos = atomicAdd(&lcnt[b], 1);
      if (pos < P1_CAP) {
        lbuf[b * P1_CAP + pos] = p;
      } else {  // rare spill: direct global scatter
        int gp = atomicAdd(&gcursor[b], 1);
        temp[(size_t)b * BCAP + gp] = p;
      }
    }
  }
  __syncthreads();
  if (tid < nbuck) {
    int c = lcnt[tid]; if (c > P1_CAP) c = P1_CAP;
    lcnt[tid] = c;
    lbase[tid] = atomicAdd(&gcursor[tid], c);
  }
  __syncthreads();
  for (int i = tid; i < nbuck * P1_CAP; i += 1024) {
    int b = i >> 6, j = i & (P1_CAP - 1);
    if (j < lcnt[b]) temp[(size_t)b * BCAP + lbase[b] + j] = lbuf[i];
  }
}

// exclusive scan over bucket counts (nbuck <= 256), one block
__global__ __launch_bounds__(256) void scan_buckets(const int* __restrict__ gcursor,
                                                    int* __restrict__ bbase,
                                                    int* __restrict__ row_ptr,
                                                    int nbuck, int n) {
  __shared__ int tmp[256];
  int t = threadIdx.x;
  int v = (t < nbuck) ? min(gcursor[t], BCAP) : 0;
  tmp[t] = v;
  __syncthreads();
  #pragma unroll
  for (int off = 1; off < 256; off <<= 1) {
    int x = (t >= off) ? tmp[t - off] : 0;
    __syncthreads();
    tmp[t] += x;
    __syncthreads();
  }
  if (t < nbuck) bbase[t] = tmp[t] - v;
  if (t == 0) row_ptr[n] = tmp[255];
}

// pass2: per-bucket local CSR. 1024 threads.
__global__ __launch_bounds__(1024) void pass2_csr(const unsigned* __restrict__ temp,
                                                  const int* __restrict__ gcursor,
                                                  const int* __restrict__ bbase,
                                                  unsigned short* __restrict__ csr16,
                                                  int* __restrict__ row_ptr,
                                                  float* __restrict__ dinv, int n) {
  __shared__ unsigned ebuf[BCAP];          // 40 KB
  __shared__ unsigned short sorted[BCAP];  // 20 KB
  __shared__ int hist[256], scn[256], sexcl[256], ofs[256];
  const int b = blockIdx.x;
  const int tid = threadIdx.x;
  int cnt = gcursor[b]; if (cnt > BCAP) cnt = BCAP;
  const int base = bbase[b];
  const unsigned* tp = temp + (size_t)b * BCAP;

  if (tid < 256) { hist[tid] = 0; ofs[tid] = 0; }
  for (int i = tid; i < cnt; i += 1024) ebuf[i] = tp[i];
  __syncthreads();
  for (int i = tid; i < cnt; i += 1024) atomicAdd(&hist[(ebuf[i] >> 16) & 255], 1);
  __syncthreads();

  if (tid < 256) scn[tid] = hist[tid];
  __syncthreads();
  #pragma unroll
  for (int off = 1; off < 256; off <<= 1) {
    int x = 0;
    if (tid < 256 && tid >= off) x = scn[tid - off];
    __syncthreads();
    if (tid < 256) scn[tid] += x;
    __syncthreads();
  }
  if (tid < 256) {
    int v = hist[tid];
    int excl = scn[tid] - v;
    sexcl[tid] = excl;
    int node = (b << 8) + tid;
    if (node < n) {
      row_ptr[node] = base + excl;
      dinv[node] = rsqrtf((float)(v + 1));  // +1 self loop
    }
  }
  __syncthreads();

  for (int i = tid; i < cnt; i += 1024) {
    unsigned e = ebuf[i];
    int dl = (int)((e >> 16) & 255);
    int pos = sexcl[dl] + atomicAdd(&ofs[dl], 1);
    sorted[pos] = (unsigned short)(e & 0xFFFFu);
  }
  __syncthreads();
  for (int i = tid; i < cnt; i += 1024) csr16[base + i] = sorted[i];
}

// ---------------- W transpose + bf16 convert: Wt[n][k] = bf16(W[k][n]) ----------------

__global__ __launch_bounds__(256) void wt_build(const float* __restrict__ W,
                                                unsigned short* __restrict__ Wt) {
  int k = blockIdx.x;
  int nn = threadIdx.x;
  Wt[nn * FEATS + k] = f2bf(W[k * FEATS + nn]);
}

// ---------------- MFMA GEMM (round-8 structure), slice-major epilogue ----------------

__global__ __launch_bounds__(256, 2) void gemm_mfma(const float* __restrict__ x,
                                                    const unsigned short* __restrict__ Wt,
                                                    const float* __restrict__ dinv,
                                                    unsigned short* __restrict__ xwp,
                                                    int M, int npad) {
  __shared__ bf16x8 A_lds[32 * 64];  // [sub*8+kc][lane], 32 KB
  const int wv   = (int)(threadIdx.x >> 6);  // wave id = col-group = conversion sub
  const int lane = (int)(threadIdx.x & 63);
  const int lm   = lane & 15;
  const int quad = lane >> 4;
  const int m0   = (int)blockIdx.x * 64;

  // B panel: loaded once, lives in registers for the whole block
  bf16x8 Bfrag[4][8];
  #pragma unroll
  for (int ct = 0; ct < 4; ++ct) {
    const unsigned short* wrow = Wt + (size_t)(wv * 64 + ct * 16 + lm) * FEATS + quad * 8;
    #pragma unroll
    for (int kc = 0; kc < 8; ++kc)
      Bfrag[ct][kc] = *(const bf16x8*)(wrow + kc * 32);
  }

  // stage A sub = wv
  {
    int arow = m0 + wv * 16 + lm; if (arow >= M) arow = M - 1;
    const float* xrow = x + (size_t)arow * FEATS + quad * 8;
    #pragma unroll
    for (int kc = 0; kc < 8; ++kc) {
      const float4 f0 = *(const float4*)(xrow + kc * 32);
      const float4 f1 = *(const float4*)(xrow + kc * 32 + 4);
      union { bf16x8 v; unsigned short u[8]; } a;
      a.u[0] = f2bf(f0.x); a.u[1] = f2bf(f0.y); a.u[2] = f2bf(f0.z); a.u[3] = f2bf(f0.w);
      a.u[4] = f2bf(f1.x); a.u[5] = f2bf(f1.y); a.u[6] = f2bf(f1.z); a.u[7] = f2bf(f1.w);
      A_lds[(wv * 8 + kc) * 64 + lane] = a.v;
    }
  }
  __syncthreads();

  // compute: 4 row-subs x (8 kc x 4 ct) MFMAs, A from LDS, B from registers
  #pragma unroll
  for (int sub = 0; sub < 4; ++sub) {
    bf16x8 Af[8];
    #pragma unroll
    for (int kc = 0; kc < 8; ++kc) Af[kc] = A_lds[(sub * 8 + kc) * 64 + lane];

    f32x4 acc[4];
    #pragma unroll
    for (int ct = 0; ct < 4; ++ct) acc[ct] = (f32x4){0.f, 0.f, 0.f, 0.f};

    #pragma unroll
    for (int kc = 0; kc < 8; ++kc) {
      #pragma unroll
      for (int ct = 0; ct < 4; ++ct)
        acc[ct] = __builtin_amdgcn_mfma_f32_16x16x32_bf16(Af[kc], Bfrag[ct][kc], acc[ct], 0, 0, 0);
    }

    #pragma unroll
    for (int r = 0; r < 4; ++r) {
      const int row = m0 + sub * 16 + quad * 4 + r;
      if (row < M) {
        const float dd = dinv[row];
        #pragma unroll
        for (int ct = 0; ct < 4; ++ct) {
          const int c = wv * 64 + ct * 16 + lm;
          const int sl = c >> 5, off = c & 31;  // slice-major write
          xwp[((size_t)sl * npad + row) * 32 + off] = f2bf(acc[ct][r] * dd);
        }
      }
    }
  }
}

// ---------------- aggregation: slice-phased, 8 nodes x 8 col-lanes per wave ----------------
// eg = lane>>3 selects the wave's node; cl = lane&7 selects 4 of the slice's 32
// cols. Per iteration: ONE idx-load instr (8 distinct 2B addrs, bcast in eg) +
// ONE gather instr (8 random 64B rows = 512 B payload) + 8 unpack/add VALU.
// No cross-lane reduce; loop to max-degree of the 8 nodes; sentinel row n
// (zeroed) absorbs finished nodes (broadcast L1-hit, cheap).

__global__ __launch_bounds__(256) void aggregate(const unsigned short* __restrict__ xwp,
                                                 const float* __restrict__ dinv,
                                                 const int* __restrict__ row_ptr,
                                                 const unsigned short* __restrict__ csr16,
                                                 const float* __restrict__ bias,
                                                 float* __restrict__ out,
                                                 int n, int npad, int nbps, int sl0) {
  const int sl   = sl0 + (int)(blockIdx.x / nbps);
  const int nb   = (int)(blockIdx.x % nbps);
  const int wv   = (int)(threadIdx.x >> 6);
  const int lane = (int)(threadIdx.x & 63);
  const int eg   = lane >> 3;   // node within wave
  const int cl   = lane & 7;    // 4-col group within slice
  const int node = nb * 32 + wv * 8 + eg;
  const bool valid = node < n;
  const int nodec = valid ? node : n;  // clamp to sentinel (zero row, deg 0)

  const unsigned short* xs = xwp + (size_t)sl * npad * 32 + cl * 4;

  // self-loop row
  uint2 v0 = *(const uint2*)(xs + (size_t)nodec * 32);
  float4 acc;
  acc.x = bflo(v0.x); acc.y = bfhi(v0.x); acc.z = bflo(v0.y); acc.w = bfhi(v0.y);

  const int beg = valid ? row_ptr[node] : 0;
  const int end = valid ? row_ptr[node + 1] : 0;
  const int deg = end - beg;
  // wave-max degree over the eg dimension (strides 8,16,32)
  int mdeg = deg;
  #pragma unroll
  for (int st = 8; st < 64; st <<= 1) mdeg = max(mdeg, __shfl_xor(mdeg, st));

  for (int t = 0; t < mdeg; t += 8) {
    int sj[8];
    uint2 vv[8];
    #pragma unroll
    for (int j = 0; j < 8; ++j) {
      const int it = t + j;
      const int a = (it < deg) ? beg + it : 0;      // in-bounds always
      sj[j] = (it < deg) ? (int)csr16[a] : n;       // sentinel for tail
    }
    #pragma unroll
    for (int j = 0; j < 8; ++j)
      vv[j] = *(const uint2*)(xs + (size_t)sj[j] * 32);
    #pragma unroll
    for (int j = 0; j < 8; ++j) {
      acc.x += bflo(vv[j].x); acc.y += bfhi(vv[j].x);
      acc.z += bflo(vv[j].y); acc.w += bfhi(vv[j].y);
    }
  }

  if (valid) {
    const float dd = dinv[node];
    const float4 bb = *(const float4*)(bias + sl * 32 + cl * 4);
    f32x4 o;
    o.x = fmaxf(fmaf(acc.x, dd, bb.x), 0.f);
    o.y = fmaxf(fmaf(acc.y, dd, bb.y), 0.f);
    o.z = fmaxf(fmaf(acc.z, dd, bb.z), 0.f);
    o.w = fmaxf(fmaf(acc.w, dd, bb.w), 0.f);
    // NT store: 51 MB output written once; keep xwp slices in L2
    __builtin_nontemporal_store(o, (f32x4*)(out + (size_t)node * 256 + sl * 32 + cl * 4));
  }
}

// ---------------- launch ----------------

extern "C" void kernel_launch(void* const* d_in, const int* in_sizes, int n_in,
                              void* d_out, int out_size, void* d_ws, size_t ws_size,
                              hipStream_t stream) {
  const float* x  = (const float*)d_in[0];   // [n, 256]
  const int*   ei = (const int*)d_in[1];     // [2, E]
  const float* W  = (const float*)d_in[2];   // [256, 256]
  const float* b  = (const float*)d_in[3];   // [256]

  const int n = in_sizes[0] / FEATS;         // 50000
  const int E = in_sizes[1] / 2;             // 1,600,000
  const int* src = ei;
  const int* dst = ei + E;
  const int nbuck = (n + 255) >> 8;          // 196
  const int npad = n + 1;                    // +1 sentinel zero row per slice

  // workspace layout (bytes); real footprint ~37.4 MB
  char* ws = (char*)d_ws;
  size_t o0 = 0;
  unsigned short* xwp   = (unsigned short*)(ws + o0); o0 += (size_t)npad * 512;  // 8 slices x npad x 64 B
  unsigned short* Wt    = (unsigned short*)(ws + o0); o0 += 131072;
  float*          dinv  = (float*)(ws + o0);          o0 += 200064;
  int*            row_ptr = (int*)(ws + o0);          o0 += 200064;
  unsigned short* csr16 = (unsigned short*)(ws + o0); o0 += 3200000;
  int*            gcursor = (int*)(ws + o0);          o0 += 1024;
  int*            bbase   = (int*)(ws + o0);          o0 += 1024;
  unsigned*       temp    = (unsigned*)(ws + o0);     o0 += (size_t)nbuck * BCAP * 4;

  hipLaunchKernelGGL(init_misc, dim3(1), dim3(512), 0, stream, gcursor, nbuck, (int*)xwp, npad, n);
  hipLaunchKernelGGL(wt_build, dim3(256), dim3(256), 0, stream, W, Wt);

  const int g_p1 = (E + 4095) / 4096;  // 391
  hipLaunchKernelGGL(pass1_bin, dim3(g_p1), dim3(1024), 0, stream, src, dst, E, nbuck, gcursor, temp);
  hipLaunchKernelGGL(scan_buckets, dim3(1), dim3(256), 0, stream, gcursor, bbase, row_ptr, nbuck, n);
  hipLaunchKernelGGL(pass2_csr, dim3(nbuck), dim3(1024), 0, stream, temp, gcursor, bbase,
                     csr16, row_ptr, dinv, n);

  hipLaunchKernelGGL(gemm_mfma, dim3((n + 63) / 64), dim3(256), 0, stream, x, Wt, dinv, xwp, n, npad);

  // slice-phased aggregate: 32 nodes per block (4 waves x 8 nodes); two
  // dispatches (slices 0-3, 4-7) for rocprof visibility
  const int nbps = (n + 31) / 32;  // node-blocks per slice
  hipLaunchKernelGGL(aggregate, dim3(nbps * 4), dim3(256), 0, stream,
                     xwp, dinv, row_ptr, csr16, b, (float*)d_out, n, npad, nbps, 0);
  hipLaunchKernelGGL(aggregate, dim3(nbps * 4), dim3(256), 0, stream,
                     xwp, dinv, row_ptr, csr16, b, (float*)d_out, n, npad, nbps, 4);
}